// Round 11
// baseline (202.818 us; speedup 1.0000x reference)
//
#include <hip/hip_runtime.h>
#include <cstdint>
#include <cstddef>

// GNN: SAGEConv(mean) + GATConv(1 head, self-loops) + log_softmax
// CSR via two-level counting sort (PART_CHUNK=8192).
// Session ledger:
//  R1: zq rows stay 32 B (3.2 MB fits per-XCD L2; 64 B rows regressed).
//  R2-R4 probes (warm): gather ~19.7us @5.2TB/s (ceiling), gat ~24.5us
//    (latency-bound), csr+gemm ~11us, pre ~9us.
//  R5: cooperative single-dispatch fusion = 990us (5x WORSE). DEAD END.
//  R6: small kernel-time cuts masked by ~8us/dispatch overhead.
//  R7: 8->6 dispatches (scan fused into k_part). Structure correct, but
//    column-sum as serial chain = 114.9us k_part.
//  R9: MLP-16 unroll -> k_part ~34us, total 194.3 (session best so far).
//    Remaining cost: column loads at stride 1564B = 196 distinct lines.
//  R10: cnt stored TRANSPOSED (bucket-major, cnt[b*nchunk+c]) -> per-bucket
//    read is 784 contiguous B (13 lines, 49 int4 loads). k_pre writes the
//    transpose (391-dword scatter/block, fire-and-forget).

typedef unsigned short ushort_t;
typedef unsigned int uint_t;
typedef __attribute__((ext_vector_type(8))) short short8;
typedef __attribute__((ext_vector_type(4))) float f32x4;
typedef __attribute__((ext_vector_type(2))) float f32x2;

__device__ inline ushort_t f2bf(float f) {
    uint_t u = __float_as_uint(f);
    uint_t r = (u + 0x7fffu + ((u >> 16) & 1u)) >> 16;   // RTNE
    return (ushort_t)r;
}
__device__ inline uint_t pkbf(float a, float b) {
    return (uint_t)f2bf(a) | ((uint_t)f2bf(b) << 16);
}

#define PART_CHUNK 8192   // edges per chunk (196 chunks)

// ---------------- P0: cvt x -> bf16+fp8, weights -> bf16^T, per-chunk bucket counts ----------------

__global__ __launch_bounds__(256) void k_pre(const float* __restrict__ x, ushort_t* __restrict__ xh,
                                             unsigned char* __restrict__ xq,
                                             const int* __restrict__ ei,
                                             int* __restrict__ cnt,
                                             const float* __restrict__ Wl, const float* __restrict__ Wr,
                                             const float* __restrict__ Wg,
                                             ushort_t* __restrict__ Wlrt, ushort_t* __restrict__ Wgt,
                                             unsigned char* __restrict__ zq,
                                             int n4, int E, int NB, int N, int nchunk) {
    __shared__ int h[512];
    int bid = blockIdx.x, tid = threadIdx.x;
    int idx = bid * 256 + tid;
    if (idx < n4) {
        float4 v = ((const float4*)x)[idx];
        ushort4 o = { f2bf(v.x), f2bf(v.y), f2bf(v.z), f2bf(v.w) };
        ((ushort4*)xh)[idx] = o;
        int r = 0;
        r = __builtin_amdgcn_cvt_pk_fp8_f32(v.x, v.y, r, false);
        r = __builtin_amdgcn_cvt_pk_fp8_f32(v.z, v.w, r, true);
        ((uint_t*)xq)[idx] = (uint_t)r;
    }
    if (bid < nchunk) {                         // block-uniform branch: bucket histogram
        for (int b = tid; b < NB; b += 256) h[b] = 0;
        __syncthreads();
        int b0 = bid * PART_CHUNK;
        int b1 = min(b0 + PART_CHUNK, E);
        for (int j = b0 + tid; j < b1; j += 256) atomicAdd(&h[ei[E + j] >> 8], 1);
        __syncthreads();
        // R10: transposed store — cnt[b][c] layout (bucket-major rows)
        for (int b = tid; b < NB; b += 256) cnt[(size_t)b * nchunk + bid] = h[b];
    } else if (bid == nchunk) {                 // zero rows (branchless tails elsewhere)
        if (tid < 16) ((uint_t*)(xq + (size_t)N * 64))[tid] = 0;
        if (tid < 8)  ((uint_t*)(zq + (size_t)N * 32))[tid] = 0;
    } else if (bid >= 512 && bid < 544) {       // weights -> bf16 transposed [n][k]
        int t = (bid - 512) * 256 + tid;        // 0..8191
        int n = t >> 7, k = t & 127;
        float v = (k < 64) ? Wl[k * 64 + n] : Wr[(k - 64) * 64 + n];
        Wlrt[n * 128 + k] = f2bf(v);
        if (t < 32 * 64) {
            int n2 = t >> 6, k2 = t & 63;
            Wgt[n2 * 64 + k2] = f2bf(Wg[k2 * 32 + n2]);
        }
    }
}

// ---------------- P1: partition (src | (dst&255)<<24), scan fused in ----------------
// Each block: totals[b] = sum_c cnt[b][c]; myoff[b] = sum_{c<bid} cnt[b][c];
// LDS exclusive scan of totals -> base; ofs[b] = base[b] + myoff[b].
// R10: cnt row is contiguous (784 B) -> 49 independent int4 loads.

__global__ __launch_bounds__(256) void k_part(const int* __restrict__ ei, const int* __restrict__ cnt,
                                              int* __restrict__ base, int* __restrict__ rowptr,
                                              uint_t* __restrict__ pairs, int E, int NB, int N,
                                              int nchunk) {
    __shared__ int tot_s[512];
    __shared__ int ofs[512];
    __shared__ int t[256];
    int tid = threadIdx.x, bid = blockIdx.x;
    int nq = nchunk >> 2;
    for (int b = tid; b < NB; b += 256) {
        const int4* row = (const int4*)(cnt + (size_t)b * nchunk);
        int tsum = 0, moff = 0;
        #pragma unroll 4
        for (int q = 0; q < nq; ++q) {
            int4 v = row[q];
            int c0 = q * 4;
            tsum += v.x + v.y + v.z + v.w;
            moff += (c0 + 0 < bid) ? v.x : 0;
            moff += (c0 + 1 < bid) ? v.y : 0;
            moff += (c0 + 2 < bid) ? v.z : 0;
            moff += (c0 + 3 < bid) ? v.w : 0;
        }
        for (int c = nq * 4; c < nchunk; ++c) {  // tail (nchunk % 4)
            int v = cnt[(size_t)b * nchunk + c];
            tsum += v;
            moff += (c < bid) ? v : 0;
        }
        tot_s[b] = tsum;
        ofs[b] = moff;
    }
    __syncthreads();
    // exclusive scan of tot_s[0..NB) (pairwise, NB <= 512)
    int v0 = (2 * tid < NB) ? tot_s[2 * tid] : 0;
    int v1 = (2 * tid + 1 < NB) ? tot_s[2 * tid + 1] : 0;
    t[tid] = v0 + v1;
    __syncthreads();
    for (int off = 1; off < 256; off <<= 1) {
        int u = (tid >= off) ? t[tid - off] : 0;
        __syncthreads();
        t[tid] += u;
        __syncthreads();
    }
    int pairExcl = (tid > 0) ? t[tid - 1] : 0;
    if (2 * tid < NB) {
        ofs[2 * tid] += pairExcl;
        if (bid == 0) base[2 * tid] = pairExcl;
    }
    if (2 * tid + 1 < NB) {
        ofs[2 * tid + 1] += pairExcl + v0;
        if (bid == 0) base[2 * tid + 1] = pairExcl + v0;
    }
    if (bid == 0 && tid == 0) { base[NB] = E; rowptr[N] = E; }
    __syncthreads();
    // scatter this chunk's edges into its disjoint per-bucket regions
    int b0 = bid * PART_CHUNK;
    int b1 = min(b0 + PART_CHUNK, E);
    for (int j = b0 + tid; j < b1; j += 256) {
        int d = ei[E + j], s = ei[j];
        int p = atomicAdd(&ofs[d >> 8], 1);      // LDS atomic only
        pairs[p] = (uint_t)s | ((uint_t)(d & 255) << 24);
    }
}

// ---------------- P2: per-bucket CSR build (windowed, L2-hot) ----------------

__global__ __launch_bounds__(256) void k_csr(const uint_t* __restrict__ pairs, const int* __restrict__ base,
                                             int* __restrict__ rowptr, int* __restrict__ csr, int N) {
    __shared__ int h[256];
    __shared__ int s[256];
    int b = blockIdx.x;
    int d0 = b << 8;
    int e0 = base[b], e1 = base[b + 1];
    int tid = threadIdx.x;
    h[tid] = 0;
    __syncthreads();
    for (int j = e0 + tid; j < e1; j += 256) atomicAdd(&h[pairs[j] >> 24], 1);
    __syncthreads();
    int v = h[tid];
    s[tid] = v;
    __syncthreads();
    for (int off = 1; off < 256; off <<= 1) {
        int u = (tid >= off) ? s[tid - off] : 0;
        __syncthreads();
        s[tid] += u;
        __syncthreads();
    }
    int excl = s[tid] - v;
    if (d0 + tid < N) rowptr[d0 + tid] = e0 + excl;
    __syncthreads();
    h[tid] = e0 + excl;
    __syncthreads();
    for (int j = e0 + tid; j < e1; j += 256) {
        uint_t p = pairs[j];
        int pos = atomicAdd(&h[p >> 24], 1);
        csr[pos] = (int)(p & 0xffffffu);
    }
}

// ---------------- P3: SAGE mean aggregation ----------------
// 16-lane group per node; sub-halves of 8 lanes take even/odd edges;
// lane covers 8 channels via one uint2 (8 B) load. Single pass.

__global__ __launch_bounds__(256) void k_gather(const int* __restrict__ rowptr, const int* __restrict__ csr,
                                                const unsigned char* __restrict__ xq,
                                                ushort_t* __restrict__ aggh, int N) {
    __shared__ int scr[256];
    int tid = threadIdx.x;
    int l = tid & 15, g = tid >> 4;
    int i = blockIdx.x * 16 + g;
    if (i >= N) return;
    int r0 = rowptr[i], r1 = rowptr[i + 1];
    int sub = l >> 3, lc = l & 7;
    const char* xb = (const char*)xq + lc * 8;
    float a0 = 0.f, a1 = 0.f, a2 = 0.f, a3 = 0.f;
    float a4 = 0.f, a5 = 0.f, a6 = 0.f, a7 = 0.f;
    for (int bb = r0; bb < r1; bb += 16) {
        int idx = bb + l;
        int src = (idx < r1) ? csr[idx] : N;      // N = zero row
        scr[tid] = src << 6;                      // 64 B fp8 row offset
        uint4 q0 = *(const uint4*)&scr[g * 16 + 0];
        uint4 q1 = *(const uint4*)&scr[g * 16 + 4];
        uint4 q2 = *(const uint4*)&scr[g * 16 + 8];
        uint4 q3 = *(const uint4*)&scr[g * 16 + 12];
#define HSTEP(oa, ob) { \
        uint_t off = sub ? (ob) : (oa); \
        uint2 u = *(const uint2*)(xb + off); \
        f32x2 p0 = __builtin_amdgcn_cvt_pk_f32_fp8((int)u.x, false); \
        f32x2 p1 = __builtin_amdgcn_cvt_pk_f32_fp8((int)u.x, true); \
        f32x2 p2 = __builtin_amdgcn_cvt_pk_f32_fp8((int)u.y, false); \
        f32x2 p3 = __builtin_amdgcn_cvt_pk_f32_fp8((int)u.y, true); \
        a0 += p0.x; a1 += p0.y; a2 += p1.x; a3 += p1.y; \
        a4 += p2.x; a5 += p2.y; a6 += p3.x; a7 += p3.y; }
        HSTEP(q0.x, q0.y) HSTEP(q0.z, q0.w)
        HSTEP(q1.x, q1.y) HSTEP(q1.z, q1.w)
        HSTEP(q2.x, q2.y) HSTEP(q2.z, q2.w)
        HSTEP(q3.x, q3.y) HSTEP(q3.z, q3.w)
#undef HSTEP
    }
    // combine even/odd-edge sub-halves (xor 8 stays inside the 16-group)
    a0 += __shfl_xor(a0, 8, 64); a1 += __shfl_xor(a1, 8, 64);
    a2 += __shfl_xor(a2, 8, 64); a3 += __shfl_xor(a3, 8, 64);
    a4 += __shfl_xor(a4, 8, 64); a5 += __shfl_xor(a5, 8, 64);
    a6 += __shfl_xor(a6, 8, 64); a7 += __shfl_xor(a7, 8, 64);
    if (sub == 0) {
        float dn = 1.0f / fmaxf((float)(r1 - r0), 1.0f);
        uint4 o = { pkbf(a0 * dn, a1 * dn), pkbf(a2 * dn, a3 * dn),
                    pkbf(a4 * dn, a5 * dn), pkbf(a6 * dn, a7 * dn) };
        *(uint4*)(aggh + (size_t)i * 64 + lc * 8) = o;
    }
}

// ---------------- P4: MFMA node GEMMs + attention scores ----------------

__global__ __launch_bounds__(256) void k_gemm(const ushort_t* __restrict__ aggh, const ushort_t* __restrict__ xh,
                                              const ushort_t* __restrict__ Wlrt, const ushort_t* __restrict__ Wgt,
                                              const float* __restrict__ b1,
                                              const float* __restrict__ att_src, const float* __restrict__ att_dst,
                                              unsigned char* __restrict__ zq, float* __restrict__ a_s,
                                              float* __restrict__ a_d, int N) {
    __shared__ ushort_t Wls[64 * 136];
    __shared__ ushort_t Wgs[32 * 72];
    __shared__ ushort_t hs[64 * 136];
    int tid = threadIdx.x;
    for (int t = tid; t < 64 * 16; t += 256) {
        int n = t >> 4, cq = t & 15;
        *(uint4*)(&Wls[n * 136 + cq * 8]) = *(const uint4*)(&Wlrt[n * 128 + cq * 8]);
    }
    for (int t = tid; t < 32 * 8; t += 256) {
        int n = t >> 3, cq = t & 7;
        *(uint4*)(&Wgs[n * 72 + cq * 8]) = *(const uint4*)(&Wgt[n * 64 + cq * 8]);
    }
    __syncthreads();

    int w = tid >> 6, lane = tid & 63;
    int c = lane & 15, quad = lane >> 4;
    int m0 = blockIdx.x * 64 + w * 16;
    int row = m0 + c;
    bool rowok = row < N;

    f32x4 acc[4] = {};
    #pragma unroll
    for (int kk = 0; kk < 4; ++kk) {
        const ushort_t* Abase = (kk < 2) ? aggh : xh;
        int koff = (kk & 1) * 32 + quad * 8;
        short8 a = {};
        if (rowok) a = *(const short8*)(Abase + (size_t)row * 64 + koff);
        #pragma unroll
        for (int nb = 0; nb < 4; ++nb) {
            short8 b = *(const short8*)(&Wls[(nb * 16 + c) * 136 + kk * 32 + quad * 8]);
            acc[nb] = __builtin_amdgcn_mfma_f32_16x16x32_bf16(a, b, acc[nb], 0, 0, 0);
        }
    }
    ushort_t* hw = &hs[w * 16 * 136];
    #pragma unroll
    for (int nb = 0; nb < 4; ++nb) {
        float bb = b1[nb * 16 + c];
        #pragma unroll
        for (int r = 0; r < 4; ++r) {
            float h = acc[nb][r] + bb;
            hw[(quad * 4 + r) * 136 + nb * 16 + c] = f2bf(fmaxf(h, 0.f));
        }
    }
    f32x4 acc2[2] = {};
    #pragma unroll
    for (int kk = 0; kk < 2; ++kk) {
        short8 a = *(const short8*)(&hw[c * 136 + kk * 32 + quad * 8]);
        #pragma unroll
        for (int nb = 0; nb < 2; ++nb) {
            short8 b = *(const short8*)(&Wgs[(nb * 16 + c) * 72 + kk * 32 + quad * 8]);
            acc2[nb] = __builtin_amdgcn_mfma_f32_16x16x32_bf16(a, b, acc2[nb], 0, 0, 0);
        }
    }
    float as0 = att_src[c], as1 = att_src[16 + c];
    float ad0 = att_dst[c], ad1 = att_dst[16 + c];
    #pragma unroll
    for (int r = 0; r < 4; ++r) {
        int grow = m0 + quad * 4 + r;
        float z0 = acc2[0][r], z1 = acc2[1][r];
        float ps = z0 * as0 + z1 * as1;
        float pd = z0 * ad0 + z1 * ad1;
        #pragma unroll
        for (int off = 8; off; off >>= 1) {
            ps += __shfl_xor(ps, off, 64);
            pd += __shfl_xor(pd, off, 64);
        }
        if (grow < N) {
            int r8 = __builtin_amdgcn_cvt_pk_fp8_f32(z0, z1, 0, false);
            unsigned char* zrow = zq + (size_t)grow * 32;
            zrow[c] = (unsigned char)(r8 & 0xff);
            zrow[16 + c] = (unsigned char)((r8 >> 8) & 0xff);
            if (c == 0) { a_s[grow] = ps; a_d[grow] = pd; }
        }
    }
}

// ---------------- P5: GAT softmax aggregation + bias + log_softmax ----------------
// 16-lane group per node; LDS-staged (offset, weight); sub-halves of 8 lanes
// take even/odd edges; lane covers 4 channels via one uint (4 B) load.

__global__ __launch_bounds__(256) void k_gat(const unsigned char* __restrict__ zq, const float* __restrict__ a_s,
                                             const float* __restrict__ a_d, const int* __restrict__ rowptr,
                                             const int* __restrict__ csr, const float* __restrict__ b2,
                                             float* __restrict__ out, int N) {
    __shared__ uint2 scr[256];
    int tid = threadIdx.x;
    int l = tid & 15, g = tid >> 4;
    int i = blockIdx.x * 16 + g;
    if (i >= N) return;
    int r0 = rowptr[i], r1 = rowptr[i + 1];
    float adi = a_d[i], asi = a_s[i];
    int sub = l >> 3, lc = l & 7;
    const char* zb = (const char*)zq + lc * 4;
    float a0 = 0.f, a1 = 0.f, a2 = 0.f, a3 = 0.f, dsum = 0.f;

    for (int bb = r0; bb < r1; bb += 16) {
        int idx = bb + l;
        bool valid = idx < r1;
        int s_l = valid ? csr[idx] : N;           // N = zero row
        float w_l = 0.f;
        if (valid) {
            float e = a_s[s_l] + adi;
            e = fmaxf(e, 0.2f * e);               // leaky_relu
            w_l = __expf(e);
            dsum += w_l;
        }
        scr[tid] = make_uint2((uint_t)(s_l << 5), __float_as_uint(w_l));
        #pragma unroll
        for (int r = 0; r < 8; ++r) {
            uint4 q = *(const uint4*)&scr[g * 16 + r * 2];
            uint_t off = sub ? q.z : q.x;
            float w = __uint_as_float(sub ? q.w : q.y);
            uint_t u = *(const uint_t*)(zb + off);
            f32x2 p0 = __builtin_amdgcn_cvt_pk_f32_fp8((int)u, false);
            f32x2 p1 = __builtin_amdgcn_cvt_pk_f32_fp8((int)u, true);
            a0 += w * p0.x; a1 += w * p0.y;
            a2 += w * p1.x; a3 += w * p1.y;
        }
    }
    #pragma unroll
    for (int off = 8; off; off >>= 1) dsum += __shfl_xor(dsum, off, 64);
    // combine even/odd sub-halves
    a0 += __shfl_xor(a0, 8, 64); a1 += __shfl_xor(a1, 8, 64);
    a2 += __shfl_xor(a2, 8, 64); a3 += __shfl_xor(a3, 8, 64);
    // self loop
    float es = asi + adi; es = fmaxf(es, 0.2f * es);
    float wse = __expf(es);
    float denom = dsum + wse;
    uint_t us = *(const uint_t*)((const char*)zq + (size_t)i * 32 + lc * 4);
    f32x2 s0 = __builtin_amdgcn_cvt_pk_f32_fp8((int)us, false);
    f32x2 s1 = __builtin_amdgcn_cvt_pk_f32_fp8((int)us, true);
    a0 += wse * s0.x; a1 += wse * s0.y;
    a2 += wse * s1.x; a3 += wse * s1.y;

    float rden = 1.0f / denom;
    float o0 = a0 * rden + b2[lc * 4 + 0];
    float o1 = a1 * rden + b2[lc * 4 + 1];
    float o2 = a2 * rden + b2[lc * 4 + 2];
    float o3 = a3 * rden + b2[lc * 4 + 3];
    // log_softmax over 32 channels (8 lanes x 4 ch; subs hold identical data)
    float m2 = fmaxf(fmaxf(o0, o1), fmaxf(o2, o3));
    #pragma unroll
    for (int off = 4; off; off >>= 1) m2 = fmaxf(m2, __shfl_xor(m2, off, 64));
    float ssum = __expf(o0 - m2) + __expf(o1 - m2) + __expf(o2 - m2) + __expf(o3 - m2);
    #pragma unroll
    for (int off = 4; off; off >>= 1) ssum += __shfl_xor(ssum, off, 64);
    float lg = m2 + __logf(ssum);
    if (sub == 0) {
        float4 r = { o0 - lg, o1 - lg, o2 - lg, o3 - lg };
        *(float4*)(out + (size_t)i * 32 + lc * 4) = r;
    }
}

// ---------------- host launch ----------------

extern "C" void kernel_launch(void* const* d_in, const int* in_sizes, int n_in,
                              void* d_out, int out_size, void* d_ws, size_t ws_size,
                              hipStream_t stream) {
    const float* x       = (const float*)d_in[0];
    const int*   ei      = (const int*)d_in[1];
    const float* Wl      = (const float*)d_in[2];
    const float* Wr      = (const float*)d_in[3];
    const float* b1      = (const float*)d_in[4];
    const float* Wg      = (const float*)d_in[5];
    const float* att_src = (const float*)d_in[6];
    const float* att_dst = (const float*)d_in[7];
    const float* b2      = (const float*)d_in[8];
    float* out = (float*)d_out;

    int N = in_sizes[0] / 64;
    int E = in_sizes[1] / 2;
    int NB = (N + 255) >> 8;
    int nchunk = (E + PART_CHUNK - 1) / PART_CHUNK;   // 196

    char* ws = (char*)d_ws;
    size_t off = 0;
    auto alloc = [&](size_t bytes) { size_t r = off; off += (bytes + 255) & ~(size_t)255; return r; };
    int* base      = (int*)(ws + alloc((size_t)(NB + 1) * 4));
    int* cnt       = (int*)(ws + alloc((size_t)NB * nchunk * 4 + 16));
    int* rowptr    = (int*)(ws + alloc((size_t)(N + 1) * 4));
    uint_t* pairs  = (uint_t*)(ws + alloc((size_t)E * 4));
    int* csr       = (int*)(ws + alloc((size_t)E * 4));
    ushort_t* xh   = (ushort_t*)(ws + alloc((size_t)N * 64 * 2));
    unsigned char* xq = (unsigned char*)(ws + alloc((size_t)(N + 1) * 64));
    ushort_t* aggh = (ushort_t*)(ws + alloc((size_t)N * 64 * 2));
    unsigned char* zq = (unsigned char*)(ws + alloc((size_t)(N + 1) * 32));
    float* a_s     = (float*)(ws + alloc((size_t)N * 4));
    float* a_d     = (float*)(ws + alloc((size_t)N * 4));
    ushort_t* Wlrt = (ushort_t*)(ws + alloc(64 * 128 * 2));
    ushort_t* Wgt  = (ushort_t*)(ws + alloc(32 * 64 * 2));

    int n4 = N * 64 / 4;
    int gpre = (n4 + 255) / 256;
    if (gpre < 545) gpre = 545;
    k_pre    <<<gpre, 256, 0, stream>>>(x, xh, xq, ei, cnt, Wl, Wr, Wg, Wlrt, Wgt, zq, n4, E, NB, N, nchunk);
    k_part   <<<nchunk, 256, 0, stream>>>(ei, cnt, base, rowptr, pairs, E, NB, N, nchunk);
    k_csr    <<<NB, 256, 0, stream>>>(pairs, base, rowptr, csr, N);
    k_gather <<<(N + 15) / 16, 256, 0, stream>>>(rowptr, csr, xq, aggh, N);
    k_gemm   <<<(N + 63) / 64, 256, 0, stream>>>(aggh, xh, Wlrt, Wgt, b1, att_src, att_dst, zq, a_s, a_d, N);
    k_gat    <<<(N + 15) / 16, 256, 0, stream>>>(zq, a_s, a_d, rowptr, csr, b2, out, N);
}

// Round 12
// 202.711 us; speedup vs baseline: 1.0005x; 1.0005x over previous
//
#include <hip/hip_runtime.h>
#include <cstdint>
#include <cstddef>

// GNN: SAGEConv(mean) + GATConv(1 head, self-loops) + log_softmax
// CSR via two-level counting sort (PART_CHUNK=8192).
// Session ledger:
//  R1: zq rows stay 32 B (3.2 MB fits per-XCD L2).
//  R2-R4 probes (warm): gather ~19.7us @5.2TB/s, gat ~24.5us (latency),
//    csr+gemm ~11us, pre ~9us. ~8us/dispatch fixed overhead dominates rest.
//  R5: cooperative fusion = 990us. DEAD END. R6: neutral.
//  R7/R9: 8->6 dispatches + MLP-16 column sum = 194.3us (best).
//  R10: cnt transpose REGRESSED (202.8): write-scatter + per-lane rows
//    uncoalesced across the wave. Reverted to R9 chunk-major.
//  R11: 6->5 dispatches — k_gather fused into k_gemm (k_gg). No cross-block
//    dep: block's 64 gemm rows = its own 64 gathered nodes. agg staged in
//    LDS [64][72] (pad 72 -> 2-way bank, free); aggh global buffer gone
//    (~4us traffic); scr overlays hs. LDS 48.6KB -> 3 blocks/CU (risk:
//    gather-phase BW at lower occupancy).

typedef unsigned short ushort_t;
typedef unsigned int uint_t;
typedef __attribute__((ext_vector_type(8))) short short8;
typedef __attribute__((ext_vector_type(4))) float f32x4;
typedef __attribute__((ext_vector_type(2))) float f32x2;

__device__ inline ushort_t f2bf(float f) {
    uint_t u = __float_as_uint(f);
    uint_t r = (u + 0x7fffu + ((u >> 16) & 1u)) >> 16;   // RTNE
    return (ushort_t)r;
}
__device__ inline uint_t pkbf(float a, float b) {
    return (uint_t)f2bf(a) | ((uint_t)f2bf(b) << 16);
}

#define PART_CHUNK 8192   // edges per chunk (196 chunks)

// ---------------- P0: cvt x -> bf16+fp8, weights -> bf16^T, per-chunk bucket counts ----------------

__global__ __launch_bounds__(256) void k_pre(const float* __restrict__ x, ushort_t* __restrict__ xh,
                                             unsigned char* __restrict__ xq,
                                             const int* __restrict__ ei,
                                             int* __restrict__ cnt,
                                             const float* __restrict__ Wl, const float* __restrict__ Wr,
                                             const float* __restrict__ Wg,
                                             ushort_t* __restrict__ Wlrt, ushort_t* __restrict__ Wgt,
                                             unsigned char* __restrict__ zq,
                                             int n4, int E, int NB, int N, int nchunk) {
    __shared__ int h[512];
    int bid = blockIdx.x, tid = threadIdx.x;
    int idx = bid * 256 + tid;
    if (idx < n4) {
        float4 v = ((const float4*)x)[idx];
        ushort4 o = { f2bf(v.x), f2bf(v.y), f2bf(v.z), f2bf(v.w) };
        ((ushort4*)xh)[idx] = o;
        int r = 0;
        r = __builtin_amdgcn_cvt_pk_fp8_f32(v.x, v.y, r, false);
        r = __builtin_amdgcn_cvt_pk_fp8_f32(v.z, v.w, r, true);
        ((uint_t*)xq)[idx] = (uint_t)r;
    }
    if (bid < nchunk) {                         // block-uniform branch: bucket histogram
        for (int b = tid; b < NB; b += 256) h[b] = 0;
        __syncthreads();
        int b0 = bid * PART_CHUNK;
        int b1 = min(b0 + PART_CHUNK, E);
        for (int j = b0 + tid; j < b1; j += 256) atomicAdd(&h[ei[E + j] >> 8], 1);
        __syncthreads();
        int* crow = cnt + (size_t)bid * NB;     // chunk-major (R9 layout)
        for (int b = tid; b < NB; b += 256) crow[b] = h[b];
    } else if (bid == nchunk) {                 // zero rows (branchless tails elsewhere)
        if (tid < 16) ((uint_t*)(xq + (size_t)N * 64))[tid] = 0;
        if (tid < 8)  ((uint_t*)(zq + (size_t)N * 32))[tid] = 0;
    } else if (bid >= 512 && bid < 544) {       // weights -> bf16 transposed [n][k]
        int t = (bid - 512) * 256 + tid;        // 0..8191
        int n = t >> 7, k = t & 127;
        float v = (k < 64) ? Wl[k * 64 + n] : Wr[(k - 64) * 64 + n];
        Wlrt[n * 128 + k] = f2bf(v);
        if (t < 32 * 64) {
            int n2 = t >> 6, k2 = t & 63;
            Wgt[n2 * 64 + k2] = f2bf(Wg[k2 * 32 + n2]);
        }
    }
}

// ---------------- P1: partition (src | (dst&255)<<24), scan fused in ----------------
// R9: MLP-16 unroll of the column sum (16 independent loads in flight).

__global__ __launch_bounds__(256) void k_part(const int* __restrict__ ei, const int* __restrict__ cnt,
                                              int* __restrict__ base, int* __restrict__ rowptr,
                                              uint_t* __restrict__ pairs, int E, int NB, int N,
                                              int nchunk) {
    __shared__ int tot_s[512];
    __shared__ int ofs[512];
    __shared__ int t[256];
    int tid = threadIdx.x, bid = blockIdx.x;
    for (int b = tid; b < NB; b += 256) {
        const int* col = cnt + b;               // column b, stride NB ints
        int tsum = 0, moff = 0;
        int c = 0;
        for (; c + 16 <= nchunk; c += 16) {     // MLP-16: independent loads
            int v[16];
            #pragma unroll
            for (int k = 0; k < 16; ++k) v[k] = col[(size_t)(c + k) * NB];
            #pragma unroll
            for (int k = 0; k < 16; ++k) {
                tsum += v[k];
                moff += (c + k < bid) ? v[k] : 0;
            }
        }
        for (; c < nchunk; ++c) {
            int v = col[(size_t)c * NB];
            tsum += v;
            moff += (c < bid) ? v : 0;
        }
        tot_s[b] = tsum;
        ofs[b] = moff;
    }
    __syncthreads();
    // exclusive scan of tot_s[0..NB) (pairwise, NB <= 512)
    int v0 = (2 * tid < NB) ? tot_s[2 * tid] : 0;
    int v1 = (2 * tid + 1 < NB) ? tot_s[2 * tid + 1] : 0;
    t[tid] = v0 + v1;
    __syncthreads();
    for (int off = 1; off < 256; off <<= 1) {
        int u = (tid >= off) ? t[tid - off] : 0;
        __syncthreads();
        t[tid] += u;
        __syncthreads();
    }
    int pairExcl = (tid > 0) ? t[tid - 1] : 0;
    if (2 * tid < NB) {
        ofs[2 * tid] += pairExcl;
        if (bid == 0) base[2 * tid] = pairExcl;
    }
    if (2 * tid + 1 < NB) {
        ofs[2 * tid + 1] += pairExcl + v0;
        if (bid == 0) base[2 * tid + 1] = pairExcl + v0;
    }
    if (bid == 0 && tid == 0) { base[NB] = E; rowptr[N] = E; }
    __syncthreads();
    // scatter this chunk's edges into its disjoint per-bucket regions
    int b0 = bid * PART_CHUNK;
    int b1 = min(b0 + PART_CHUNK, E);
    for (int j = b0 + tid; j < b1; j += 256) {
        int d = ei[E + j], s = ei[j];
        int p = atomicAdd(&ofs[d >> 8], 1);      // LDS atomic only
        pairs[p] = (uint_t)s | ((uint_t)(d & 255) << 24);
    }
}

// ---------------- P2: per-bucket CSR build (windowed, L2-hot) ----------------

__global__ __launch_bounds__(256) void k_csr(const uint_t* __restrict__ pairs, const int* __restrict__ base,
                                             int* __restrict__ rowptr, int* __restrict__ csr, int N) {
    __shared__ int h[256];
    __shared__ int s[256];
    int b = blockIdx.x;
    int d0 = b << 8;
    int e0 = base[b], e1 = base[b + 1];
    int tid = threadIdx.x;
    h[tid] = 0;
    __syncthreads();
    for (int j = e0 + tid; j < e1; j += 256) atomicAdd(&h[pairs[j] >> 24], 1);
    __syncthreads();
    int v = h[tid];
    s[tid] = v;
    __syncthreads();
    for (int off = 1; off < 256; off <<= 1) {
        int u = (tid >= off) ? s[tid - off] : 0;
        __syncthreads();
        s[tid] += u;
        __syncthreads();
    }
    int excl = s[tid] - v;
    if (d0 + tid < N) rowptr[d0 + tid] = e0 + excl;
    __syncthreads();
    h[tid] = e0 + excl;
    __syncthreads();
    for (int j = e0 + tid; j < e1; j += 256) {
        uint_t p = pairs[j];
        int pos = atomicAdd(&h[p >> 24], 1);
        csr[pos] = (int)(p & 0xffffffu);
    }
}

// ---------------- P3: FUSED SAGE gather + MFMA GEMMs + attention scores ----------------
// Block owns 64 nodes. Phase A: gather means into LDS agg[64][72] (16-lane
// group per node x 4 reps; scr overlays hs). Phase B: the two MFMA GEMMs
// with A read from LDS (aggh global buffer eliminated).

__global__ __launch_bounds__(256) void k_gg(const int* __restrict__ rowptr, const int* __restrict__ csr,
                                            const unsigned char* __restrict__ xq,
                                            const ushort_t* __restrict__ xh,
                                            const ushort_t* __restrict__ Wlrt, const ushort_t* __restrict__ Wgt,
                                            const float* __restrict__ b1,
                                            const float* __restrict__ att_src, const float* __restrict__ att_dst,
                                            unsigned char* __restrict__ zq, float* __restrict__ a_s,
                                            float* __restrict__ a_d, int N) {
    __shared__ ushort_t Wls[64 * 136];                 // 17408 B
    __shared__ ushort_t Wgs[32 * 72];                  //  4608 B
    __shared__ ushort_t agg[64 * 72];                  //  9216 B (pad 72)
    __shared__ __align__(16) char hsraw[64 * 136 * 2]; // 17408 B (phase B) / scr (phase A)
    int tid = threadIdx.x;
    int blk = blockIdx.x;

    // stage weights (phase-B data; sync below covers it)
    for (int t = tid; t < 64 * 16; t += 256) {
        int n = t >> 4, cq = t & 15;
        *(uint4*)(&Wls[n * 136 + cq * 8]) = *(const uint4*)(&Wlrt[n * 128 + cq * 8]);
    }
    for (int t = tid; t < 32 * 8; t += 256) {
        int n = t >> 3, cq = t & 7;
        *(uint4*)(&Wgs[n * 72 + cq * 8]) = *(const uint4*)(&Wgt[n * 64 + cq * 8]);
    }

    // ---- Phase A: gather 64 nodes into agg LDS
    {
        int* scr = (int*)hsraw;
        int l = tid & 15, g = tid >> 4;
        int sub = l >> 3, lc = l & 7;
        const char* xb = (const char*)xq + lc * 8;
        #pragma unroll
        for (int rep = 0; rep < 4; ++rep) {
            int ilocal = rep * 16 + g;
            int i = blk * 64 + ilocal;
            if (i < N) {
                int r0 = rowptr[i], r1 = rowptr[i + 1];
                float a0 = 0.f, a1 = 0.f, a2 = 0.f, a3 = 0.f;
                float a4 = 0.f, a5 = 0.f, a6 = 0.f, a7 = 0.f;
                for (int bb = r0; bb < r1; bb += 16) {
                    int idx = bb + l;
                    int src = (idx < r1) ? csr[idx] : N;  // N = zero row
                    scr[tid] = src << 6;                  // 64 B fp8 row offset
                    uint4 q0 = *(const uint4*)&scr[g * 16 + 0];
                    uint4 q1 = *(const uint4*)&scr[g * 16 + 4];
                    uint4 q2 = *(const uint4*)&scr[g * 16 + 8];
                    uint4 q3 = *(const uint4*)&scr[g * 16 + 12];
#define HSTEP(oa, ob) { \
                    uint_t off = sub ? (ob) : (oa); \
                    uint2 u = *(const uint2*)(xb + off); \
                    f32x2 p0 = __builtin_amdgcn_cvt_pk_f32_fp8((int)u.x, false); \
                    f32x2 p1 = __builtin_amdgcn_cvt_pk_f32_fp8((int)u.x, true); \
                    f32x2 p2 = __builtin_amdgcn_cvt_pk_f32_fp8((int)u.y, false); \
                    f32x2 p3 = __builtin_amdgcn_cvt_pk_f32_fp8((int)u.y, true); \
                    a0 += p0.x; a1 += p0.y; a2 += p1.x; a3 += p1.y; \
                    a4 += p2.x; a5 += p2.y; a6 += p3.x; a7 += p3.y; }
                    HSTEP(q0.x, q0.y) HSTEP(q0.z, q0.w)
                    HSTEP(q1.x, q1.y) HSTEP(q1.z, q1.w)
                    HSTEP(q2.x, q2.y) HSTEP(q2.z, q2.w)
                    HSTEP(q3.x, q3.y) HSTEP(q3.z, q3.w)
#undef HSTEP
                }
                a0 += __shfl_xor(a0, 8, 64); a1 += __shfl_xor(a1, 8, 64);
                a2 += __shfl_xor(a2, 8, 64); a3 += __shfl_xor(a3, 8, 64);
                a4 += __shfl_xor(a4, 8, 64); a5 += __shfl_xor(a5, 8, 64);
                a6 += __shfl_xor(a6, 8, 64); a7 += __shfl_xor(a7, 8, 64);
                if (sub == 0) {
                    float dn = 1.0f / fmaxf((float)(r1 - r0), 1.0f);
                    uint4 o = { pkbf(a0 * dn, a1 * dn), pkbf(a2 * dn, a3 * dn),
                                pkbf(a4 * dn, a5 * dn), pkbf(a6 * dn, a7 * dn) };
                    *(uint4*)(&agg[ilocal * 72 + lc * 8]) = o;
                }
            }
        }
    }
    __syncthreads();

    // ---- Phase B: node GEMMs (A from LDS agg / global xh)
    ushort_t* hs = (ushort_t*)hsraw;
    int w = tid >> 6, lane = tid & 63;
    int c = lane & 15, quad = lane >> 4;
    int m0 = blk * 64 + w * 16;
    int row = m0 + c;
    bool rowok = row < N;

    f32x4 acc[4] = {};
    #pragma unroll
    for (int kk = 0; kk < 4; ++kk) {
        int koff = (kk & 1) * 32 + quad * 8;
        short8 a = {};
        if (rowok) {
            if (kk < 2) a = *(const short8*)(&agg[(w * 16 + c) * 72 + koff]);
            else        a = *(const short8*)(xh + (size_t)row * 64 + koff);
        }
        #pragma unroll
        for (int nb = 0; nb < 4; ++nb) {
            short8 b = *(const short8*)(&Wls[(nb * 16 + c) * 136 + kk * 32 + quad * 8]);
            acc[nb] = __builtin_amdgcn_mfma_f32_16x16x32_bf16(a, b, acc[nb], 0, 0, 0);
        }
    }
    ushort_t* hw = &hs[w * 16 * 136];
    #pragma unroll
    for (int nb = 0; nb < 4; ++nb) {
        float bb = b1[nb * 16 + c];
        #pragma unroll
        for (int r = 0; r < 4; ++r) {
            float h = acc[nb][r] + bb;
            hw[(quad * 4 + r) * 136 + nb * 16 + c] = f2bf(fmaxf(h, 0.f));
        }
    }
    f32x4 acc2[2] = {};
    #pragma unroll
    for (int kk = 0; kk < 2; ++kk) {
        short8 a = *(const short8*)(&hw[c * 136 + kk * 32 + quad * 8]);
        #pragma unroll
        for (int nb = 0; nb < 2; ++nb) {
            short8 b = *(const short8*)(&Wgs[(nb * 16 + c) * 72 + kk * 32 + quad * 8]);
            acc2[nb] = __builtin_amdgcn_mfma_f32_16x16x32_bf16(a, b, acc2[nb], 0, 0, 0);
        }
    }
    float as0 = att_src[c], as1 = att_src[16 + c];
    float ad0 = att_dst[c], ad1 = att_dst[16 + c];
    #pragma unroll
    for (int r = 0; r < 4; ++r) {
        int grow = m0 + quad * 4 + r;
        float z0 = acc2[0][r], z1 = acc2[1][r];
        float ps = z0 * as0 + z1 * as1;
        float pd = z0 * ad0 + z1 * ad1;
        #pragma unroll
        for (int off = 8; off; off >>= 1) {
            ps += __shfl_xor(ps, off, 64);
            pd += __shfl_xor(pd, off, 64);
        }
        if (grow < N) {
            int r8 = __builtin_amdgcn_cvt_pk_fp8_f32(z0, z1, 0, false);
            unsigned char* zrow = zq + (size_t)grow * 32;
            zrow[c] = (unsigned char)(r8 & 0xff);
            zrow[16 + c] = (unsigned char)((r8 >> 8) & 0xff);
            if (c == 0) { a_s[grow] = ps; a_d[grow] = pd; }
        }
    }
}

// ---------------- P4: GAT softmax aggregation + bias + log_softmax ----------------
// 16-lane group per node; LDS-staged (offset, weight); sub-halves of 8 lanes
// take even/odd edges; lane covers 4 channels via one uint (4 B) load.

__global__ __launch_bounds__(256) void k_gat(const unsigned char* __restrict__ zq, const float* __restrict__ a_s,
                                             const float* __restrict__ a_d, const int* __restrict__ rowptr,
                                             const int* __restrict__ csr, const float* __restrict__ b2,
                                             float* __restrict__ out, int N) {
    __shared__ uint2 scr[256];
    int tid = threadIdx.x;
    int l = tid & 15, g = tid >> 4;
    int i = blockIdx.x * 16 + g;
    if (i >= N) return;
    int r0 = rowptr[i], r1 = rowptr[i + 1];
    float adi = a_d[i], asi = a_s[i];
    int sub = l >> 3, lc = l & 7;
    const char* zb = (const char*)zq + lc * 4;
    float a0 = 0.f, a1 = 0.f, a2 = 0.f, a3 = 0.f, dsum = 0.f;

    for (int bb = r0; bb < r1; bb += 16) {
        int idx = bb + l;
        bool valid = idx < r1;
        int s_l = valid ? csr[idx] : N;           // N = zero row
        float w_l = 0.f;
        if (valid) {
            float e = a_s[s_l] + adi;
            e = fmaxf(e, 0.2f * e);               // leaky_relu
            w_l = __expf(e);
            dsum += w_l;
        }
        scr[tid] = make_uint2((uint_t)(s_l << 5), __float_as_uint(w_l));
        #pragma unroll
        for (int r = 0; r < 8; ++r) {
            uint4 q = *(const uint4*)&scr[g * 16 + r * 2];
            uint_t off = sub ? q.z : q.x;
            float w = __uint_as_float(sub ? q.w : q.y);
            uint_t u = *(const uint_t*)(zb + off);
            f32x2 p0 = __builtin_amdgcn_cvt_pk_f32_fp8((int)u, false);
            f32x2 p1 = __builtin_amdgcn_cvt_pk_f32_fp8((int)u, true);
            a0 += w * p0.x; a1 += w * p0.y;
            a2 += w * p1.x; a3 += w * p1.y;
        }
    }
    #pragma unroll
    for (int off = 8; off; off >>= 1) dsum += __shfl_xor(dsum, off, 64);
    // combine even/odd sub-halves
    a0 += __shfl_xor(a0, 8, 64); a1 += __shfl_xor(a1, 8, 64);
    a2 += __shfl_xor(a2, 8, 64); a3 += __shfl_xor(a3, 8, 64);
    // self loop
    float es = asi + adi; es = fmaxf(es, 0.2f * es);
    float wse = __expf(es);
    float denom = dsum + wse;
    uint_t us = *(const uint_t*)((const char*)zq + (size_t)i * 32 + lc * 4);
    f32x2 s0 = __builtin_amdgcn_cvt_pk_f32_fp8((int)us, false);
    f32x2 s1 = __builtin_amdgcn_cvt_pk_f32_fp8((int)us, true);
    a0 += wse * s0.x; a1 += wse * s0.y;
    a2 += wse * s1.x; a3 += wse * s1.y;

    float rden = 1.0f / denom;
    float o0 = a0 * rden + b2[lc * 4 + 0];
    float o1 = a1 * rden + b2[lc * 4 + 1];
    float o2 = a2 * rden + b2[lc * 4 + 2];
    float o3 = a3 * rden + b2[lc * 4 + 3];
    // log_softmax over 32 channels (8 lanes x 4 ch; subs hold identical data)
    float m2 = fmaxf(fmaxf(o0, o1), fmaxf(o2, o3));
    #pragma unroll
    for (int off = 4; off; off >>= 1) m2 = fmaxf(m2, __shfl_xor(m2, off, 64));
    float ssum = __expf(o0 - m2) + __expf(o1 - m2) + __expf(o2 - m2) + __expf(o3 - m2);
    #pragma unroll
    for (int off = 4; off; off >>= 1) ssum += __shfl_xor(ssum, off, 64);
    float lg = m2 + __logf(ssum);
    if (sub == 0) {
        float4 r = { o0 - lg, o1 - lg, o2 - lg, o3 - lg };
        *(float4*)(out + (size_t)i * 32 + lc * 4) = r;
    }
}

// ---------------- host launch ----------------

extern "C" void kernel_launch(void* const* d_in, const int* in_sizes, int n_in,
                              void* d_out, int out_size, void* d_ws, size_t ws_size,
                              hipStream_t stream) {
    const float* x       = (const float*)d_in[0];
    const int*   ei      = (const int*)d_in[1];
    const float* Wl      = (const float*)d_in[2];
    const float* Wr      = (const float*)d_in[3];
    const float* b1      = (const float*)d_in[4];
    const float* Wg      = (const float*)d_in[5];
    const float* att_src = (const float*)d_in[6];
    const float* att_dst = (const float*)d_in[7];
    const float* b2      = (const float*)d_in[8];
    float* out = (float*)d_out;

    int N = in_sizes[0] / 64;
    int E = in_sizes[1] / 2;
    int NB = (N + 255) >> 8;
    int nchunk = (E + PART_CHUNK - 1) / PART_CHUNK;   // 196

    char* ws = (char*)d_ws;
    size_t off = 0;
    auto alloc = [&](size_t bytes) { size_t r = off; off += (bytes + 255) & ~(size_t)255; return r; };
    int* base      = (int*)(ws + alloc((size_t)(NB + 1) * 4));
    int* cnt       = (int*)(ws + alloc((size_t)nchunk * NB * 4));
    int* rowptr    = (int*)(ws + alloc((size_t)(N + 1) * 4));
    uint_t* pairs  = (uint_t*)(ws + alloc((size_t)E * 4));
    int* csr       = (int*)(ws + alloc((size_t)E * 4));
    ushort_t* xh   = (ushort_t*)(ws + alloc((size_t)N * 64 * 2));
    unsigned char* xq = (unsigned char*)(ws + alloc((size_t)(N + 1) * 64));
    unsigned char* zq = (unsigned char*)(ws + alloc((size_t)(N + 1) * 32));
    float* a_s     = (float*)(ws + alloc((size_t)N * 4));
    float* a_d     = (float*)(ws + alloc((size_t)N * 4));
    ushort_t* Wlrt = (ushort_t*)(ws + alloc(64 * 128 * 2));
    ushort_t* Wgt  = (ushort_t*)(ws + alloc(32 * 64 * 2));

    int n4 = N * 64 / 4;
    int gpre = (n4 + 255) / 256;
    if (gpre < 545) gpre = 545;
    k_pre  <<<gpre, 256, 0, stream>>>(x, xh, xq, ei, cnt, Wl, Wr, Wg, Wlrt, Wgt, zq, n4, E, NB, N, nchunk);
    k_part <<<nchunk, 256, 0, stream>>>(ei, cnt, base, rowptr, pairs, E, NB, N, nchunk);
    k_csr  <<<NB, 256, 0, stream>>>(pairs, base, rowptr, csr, N);
    k_gg   <<<(N + 63) / 64, 256, 0, stream>>>(rowptr, csr, xq, xh, Wlrt, Wgt, b1, att_src, att_dst, zq, a_s, a_d, N);
    k_gat  <<<(N + 15) / 16, 256, 0, stream>>>(zq, a_s, a_d, rowptr, csr, b2, out, N);
}

// Round 13
// 194.311 us; speedup vs baseline: 1.0438x; 1.0432x over previous
//
#include <hip/hip_runtime.h>
#include <cstdint>
#include <cstddef>

// GNN: SAGEConv(mean) + GATConv(1 head, self-loops) + log_softmax
// CSR via two-level counting sort (PART_CHUNK=8192).
// Session ledger:
//  R1: zq rows stay 32 B (3.2 MB fits per-XCD L2).
//  R2-R4 probes (warm): gather ~19.7us @5.2TB/s, gat ~24.5us (latency),
//    csr+gemm ~11us, pre ~9us. ~8us/dispatch fixed overhead.
//  R5: cooperative fusion = 990us. DEAD END.
//  R7/R9: 8->6 dispatches + MLP-16 column sum = 194.3us (session best).
//  R10: cnt transpose REGRESSED (write-scatter + uncoalesced wave reads).
//  R11: gather+gemm fusion REGRESSED (202.7): k_gg Occ 24% (48.6KB LDS ->
//    3 blk/CU) strangled the gather phase (5.2 -> 1.2 TB/s). Lesson:
//    never fuse a high-occupancy memory phase into a high-LDS kernel.
//  R12: revert to R9 structure; k_part block 256 -> 1024 threads (same 196
//    blocks, 16 waves/CU vs 4 — both phases latency-bound at Occ 7.8%).

typedef unsigned short ushort_t;
typedef unsigned int uint_t;
typedef __attribute__((ext_vector_type(8))) short short8;
typedef __attribute__((ext_vector_type(4))) float f32x4;
typedef __attribute__((ext_vector_type(2))) float f32x2;

__device__ inline ushort_t f2bf(float f) {
    uint_t u = __float_as_uint(f);
    uint_t r = (u + 0x7fffu + ((u >> 16) & 1u)) >> 16;   // RTNE
    return (ushort_t)r;
}
__device__ inline uint_t pkbf(float a, float b) {
    return (uint_t)f2bf(a) | ((uint_t)f2bf(b) << 16);
}

#define PART_CHUNK 8192   // edges per chunk (196 chunks)

// ---------------- P0: cvt x -> bf16+fp8, weights -> bf16^T, per-chunk bucket counts ----------------

__global__ __launch_bounds__(256) void k_pre(const float* __restrict__ x, ushort_t* __restrict__ xh,
                                             unsigned char* __restrict__ xq,
                                             const int* __restrict__ ei,
                                             int* __restrict__ cnt,
                                             const float* __restrict__ Wl, const float* __restrict__ Wr,
                                             const float* __restrict__ Wg,
                                             ushort_t* __restrict__ Wlrt, ushort_t* __restrict__ Wgt,
                                             unsigned char* __restrict__ zq,
                                             int n4, int E, int NB, int N, int nchunk) {
    __shared__ int h[512];
    int bid = blockIdx.x, tid = threadIdx.x;
    int idx = bid * 256 + tid;
    if (idx < n4) {
        float4 v = ((const float4*)x)[idx];
        ushort4 o = { f2bf(v.x), f2bf(v.y), f2bf(v.z), f2bf(v.w) };
        ((ushort4*)xh)[idx] = o;
        int r = 0;
        r = __builtin_amdgcn_cvt_pk_fp8_f32(v.x, v.y, r, false);
        r = __builtin_amdgcn_cvt_pk_fp8_f32(v.z, v.w, r, true);
        ((uint_t*)xq)[idx] = (uint_t)r;
    }
    if (bid < nchunk) {                         // block-uniform branch: bucket histogram
        for (int b = tid; b < NB; b += 256) h[b] = 0;
        __syncthreads();
        int b0 = bid * PART_CHUNK;
        int b1 = min(b0 + PART_CHUNK, E);
        for (int j = b0 + tid; j < b1; j += 256) atomicAdd(&h[ei[E + j] >> 8], 1);
        __syncthreads();
        int* crow = cnt + (size_t)bid * NB;     // chunk-major (R9 layout)
        for (int b = tid; b < NB; b += 256) crow[b] = h[b];
    } else if (bid == nchunk) {                 // zero rows (branchless tails elsewhere)
        if (tid < 16) ((uint_t*)(xq + (size_t)N * 64))[tid] = 0;
        if (tid < 8)  ((uint_t*)(zq + (size_t)N * 32))[tid] = 0;
    } else if (bid >= 512 && bid < 544) {       // weights -> bf16 transposed [n][k]
        int t = (bid - 512) * 256 + tid;        // 0..8191
        int n = t >> 7, k = t & 127;
        float v = (k < 64) ? Wl[k * 64 + n] : Wr[(k - 64) * 64 + n];
        Wlrt[n * 128 + k] = f2bf(v);
        if (t < 32 * 64) {
            int n2 = t >> 6, k2 = t & 63;
            Wgt[n2 * 64 + k2] = f2bf(Wg[k2 * 32 + n2]);
        }
    }
}

// ---------------- P1: partition (src | (dst&255)<<24), scan fused in ----------------
// R9: MLP-16 unroll of the column sum. R12: 1024 threads/block (16 waves/CU
// on the 196 active CUs) to hide latency in both sum and scatter phases.
// Barriers are all-thread-uniform; computation is guarded.

__global__ __launch_bounds__(1024) void k_part(const int* __restrict__ ei, const int* __restrict__ cnt,
                                               int* __restrict__ base, int* __restrict__ rowptr,
                                               uint_t* __restrict__ pairs, int E, int NB, int N,
                                               int nchunk) {
    __shared__ int tot_s[512];
    __shared__ int ofs[512];
    __shared__ int t[256];
    int tid = threadIdx.x, bid = blockIdx.x;
    for (int b = tid; b < NB; b += 1024) {      // <=1 bucket/thread (NB=391)
        const int* col = cnt + b;               // column b, stride NB ints
        int tsum = 0, moff = 0;
        int c = 0;
        for (; c + 16 <= nchunk; c += 16) {     // MLP-16: independent loads
            int v[16];
            #pragma unroll
            for (int k = 0; k < 16; ++k) v[k] = col[(size_t)(c + k) * NB];
            #pragma unroll
            for (int k = 0; k < 16; ++k) {
                tsum += v[k];
                moff += (c + k < bid) ? v[k] : 0;
            }
        }
        for (; c < nchunk; ++c) {
            int v = col[(size_t)c * NB];
            tsum += v;
            moff += (c < bid) ? v : 0;
        }
        tot_s[b] = tsum;
        ofs[b] = moff;
    }
    __syncthreads();
    // exclusive scan of tot_s[0..NB) — threads 0..255 compute, all sync
    int v0 = 0, v1 = 0;
    if (tid < 256) {
        v0 = (2 * tid < NB) ? tot_s[2 * tid] : 0;
        v1 = (2 * tid + 1 < NB) ? tot_s[2 * tid + 1] : 0;
        t[tid] = v0 + v1;
    }
    __syncthreads();
    for (int off = 1; off < 256; off <<= 1) {
        int u = (tid >= off && tid < 256) ? t[tid - off] : 0;
        __syncthreads();
        if (tid < 256) t[tid] += u;
        __syncthreads();
    }
    if (tid < 256) {
        int pairExcl = (tid > 0) ? t[tid - 1] : 0;
        if (2 * tid < NB) {
            ofs[2 * tid] += pairExcl;
            if (bid == 0) base[2 * tid] = pairExcl;
        }
        if (2 * tid + 1 < NB) {
            ofs[2 * tid + 1] += pairExcl + v0;
            if (bid == 0) base[2 * tid + 1] = pairExcl + v0;
        }
        if (bid == 0 && tid == 0) { base[NB] = E; rowptr[N] = E; }
    }
    __syncthreads();
    // scatter this chunk's edges into its disjoint per-bucket regions
    int b0 = bid * PART_CHUNK;
    int b1 = min(b0 + PART_CHUNK, E);
    for (int j = b0 + tid; j < b1; j += 1024) {
        int d = ei[E + j], s = ei[j];
        int p = atomicAdd(&ofs[d >> 8], 1);      // LDS atomic only
        pairs[p] = (uint_t)s | ((uint_t)(d & 255) << 24);
    }
}

// ---------------- P2: per-bucket CSR build (windowed, L2-hot) ----------------

__global__ __launch_bounds__(256) void k_csr(const uint_t* __restrict__ pairs, const int* __restrict__ base,
                                             int* __restrict__ rowptr, int* __restrict__ csr, int N) {
    __shared__ int h[256];
    __shared__ int s[256];
    int b = blockIdx.x;
    int d0 = b << 8;
    int e0 = base[b], e1 = base[b + 1];
    int tid = threadIdx.x;
    h[tid] = 0;
    __syncthreads();
    for (int j = e0 + tid; j < e1; j += 256) atomicAdd(&h[pairs[j] >> 24], 1);
    __syncthreads();
    int v = h[tid];
    s[tid] = v;
    __syncthreads();
    for (int off = 1; off < 256; off <<= 1) {
        int u = (tid >= off) ? s[tid - off] : 0;
        __syncthreads();
        s[tid] += u;
        __syncthreads();
    }
    int excl = s[tid] - v;
    if (d0 + tid < N) rowptr[d0 + tid] = e0 + excl;
    __syncthreads();
    h[tid] = e0 + excl;
    __syncthreads();
    for (int j = e0 + tid; j < e1; j += 256) {
        uint_t p = pairs[j];
        int pos = atomicAdd(&h[p >> 24], 1);
        csr[pos] = (int)(p & 0xffffffu);
    }
}

// ---------------- P3: SAGE mean aggregation ----------------
// 16-lane group per node; sub-halves of 8 lanes take even/odd edges;
// lane covers 8 channels via one uint2 (8 B) load. Single pass.

__global__ __launch_bounds__(256) void k_gather(const int* __restrict__ rowptr, const int* __restrict__ csr,
                                                const unsigned char* __restrict__ xq,
                                                ushort_t* __restrict__ aggh, int N) {
    __shared__ int scr[256];
    int tid = threadIdx.x;
    int l = tid & 15, g = tid >> 4;
    int i = blockIdx.x * 16 + g;
    if (i >= N) return;
    int r0 = rowptr[i], r1 = rowptr[i + 1];
    int sub = l >> 3, lc = l & 7;
    const char* xb = (const char*)xq + lc * 8;
    float a0 = 0.f, a1 = 0.f, a2 = 0.f, a3 = 0.f;
    float a4 = 0.f, a5 = 0.f, a6 = 0.f, a7 = 0.f;
    for (int bb = r0; bb < r1; bb += 16) {
        int idx = bb + l;
        int src = (idx < r1) ? csr[idx] : N;      // N = zero row
        scr[tid] = src << 6;                      // 64 B fp8 row offset
        uint4 q0 = *(const uint4*)&scr[g * 16 + 0];
        uint4 q1 = *(const uint4*)&scr[g * 16 + 4];
        uint4 q2 = *(const uint4*)&scr[g * 16 + 8];
        uint4 q3 = *(const uint4*)&scr[g * 16 + 12];
#define HSTEP(oa, ob) { \
        uint_t off = sub ? (ob) : (oa); \
        uint2 u = *(const uint2*)(xb + off); \
        f32x2 p0 = __builtin_amdgcn_cvt_pk_f32_fp8((int)u.x, false); \
        f32x2 p1 = __builtin_amdgcn_cvt_pk_f32_fp8((int)u.x, true); \
        f32x2 p2 = __builtin_amdgcn_cvt_pk_f32_fp8((int)u.y, false); \
        f32x2 p3 = __builtin_amdgcn_cvt_pk_f32_fp8((int)u.y, true); \
        a0 += p0.x; a1 += p0.y; a2 += p1.x; a3 += p1.y; \
        a4 += p2.x; a5 += p2.y; a6 += p3.x; a7 += p3.y; }
        HSTEP(q0.x, q0.y) HSTEP(q0.z, q0.w)
        HSTEP(q1.x, q1.y) HSTEP(q1.z, q1.w)
        HSTEP(q2.x, q2.y) HSTEP(q2.z, q2.w)
        HSTEP(q3.x, q3.y) HSTEP(q3.z, q3.w)
#undef HSTEP
    }
    // combine even/odd-edge sub-halves (xor 8 stays inside the 16-group)
    a0 += __shfl_xor(a0, 8, 64); a1 += __shfl_xor(a1, 8, 64);
    a2 += __shfl_xor(a2, 8, 64); a3 += __shfl_xor(a3, 8, 64);
    a4 += __shfl_xor(a4, 8, 64); a5 += __shfl_xor(a5, 8, 64);
    a6 += __shfl_xor(a6, 8, 64); a7 += __shfl_xor(a7, 8, 64);
    if (sub == 0) {
        float dn = 1.0f / fmaxf((float)(r1 - r0), 1.0f);
        uint4 o = { pkbf(a0 * dn, a1 * dn), pkbf(a2 * dn, a3 * dn),
                    pkbf(a4 * dn, a5 * dn), pkbf(a6 * dn, a7 * dn) };
        *(uint4*)(aggh + (size_t)i * 64 + lc * 8) = o;
    }
}

// ---------------- P4: MFMA node GEMMs + attention scores ----------------

__global__ __launch_bounds__(256) void k_gemm(const ushort_t* __restrict__ aggh, const ushort_t* __restrict__ xh,
                                              const ushort_t* __restrict__ Wlrt, const ushort_t* __restrict__ Wgt,
                                              const float* __restrict__ b1,
                                              const float* __restrict__ att_src, const float* __restrict__ att_dst,
                                              unsigned char* __restrict__ zq, float* __restrict__ a_s,
                                              float* __restrict__ a_d, int N) {
    __shared__ ushort_t Wls[64 * 136];
    __shared__ ushort_t Wgs[32 * 72];
    __shared__ ushort_t hs[64 * 136];
    int tid = threadIdx.x;
    for (int t = tid; t < 64 * 16; t += 256) {
        int n = t >> 4, cq = t & 15;
        *(uint4*)(&Wls[n * 136 + cq * 8]) = *(const uint4*)(&Wlrt[n * 128 + cq * 8]);
    }
    for (int t = tid; t < 32 * 8; t += 256) {
        int n = t >> 3, cq = t & 7;
        *(uint4*)(&Wgs[n * 72 + cq * 8]) = *(const uint4*)(&Wgt[n * 64 + cq * 8]);
    }
    __syncthreads();

    int w = tid >> 6, lane = tid & 63;
    int c = lane & 15, quad = lane >> 4;
    int m0 = blockIdx.x * 64 + w * 16;
    int row = m0 + c;
    bool rowok = row < N;

    f32x4 acc[4] = {};
    #pragma unroll
    for (int kk = 0; kk < 4; ++kk) {
        const ushort_t* Abase = (kk < 2) ? aggh : xh;
        int koff = (kk & 1) * 32 + quad * 8;
        short8 a = {};
        if (rowok) a = *(const short8*)(Abase + (size_t)row * 64 + koff);
        #pragma unroll
        for (int nb = 0; nb < 4; ++nb) {
            short8 b = *(const short8*)(&Wls[(nb * 16 + c) * 136 + kk * 32 + quad * 8]);
            acc[nb] = __builtin_amdgcn_mfma_f32_16x16x32_bf16(a, b, acc[nb], 0, 0, 0);
        }
    }
    ushort_t* hw = &hs[w * 16 * 136];
    #pragma unroll
    for (int nb = 0; nb < 4; ++nb) {
        float bb = b1[nb * 16 + c];
        #pragma unroll
        for (int r = 0; r < 4; ++r) {
            float h = acc[nb][r] + bb;
            hw[(quad * 4 + r) * 136 + nb * 16 + c] = f2bf(fmaxf(h, 0.f));
        }
    }
    f32x4 acc2[2] = {};
    #pragma unroll
    for (int kk = 0; kk < 2; ++kk) {
        short8 a = *(const short8*)(&hw[c * 136 + kk * 32 + quad * 8]);
        #pragma unroll
        for (int nb = 0; nb < 2; ++nb) {
            short8 b = *(const short8*)(&Wgs[(nb * 16 + c) * 72 + kk * 32 + quad * 8]);
            acc2[nb] = __builtin_amdgcn_mfma_f32_16x16x32_bf16(a, b, acc2[nb], 0, 0, 0);
        }
    }
    float as0 = att_src[c], as1 = att_src[16 + c];
    float ad0 = att_dst[c], ad1 = att_dst[16 + c];
    #pragma unroll
    for (int r = 0; r < 4; ++r) {
        int grow = m0 + quad * 4 + r;
        float z0 = acc2[0][r], z1 = acc2[1][r];
        float ps = z0 * as0 + z1 * as1;
        float pd = z0 * ad0 + z1 * ad1;
        #pragma unroll
        for (int off = 8; off; off >>= 1) {
            ps += __shfl_xor(ps, off, 64);
            pd += __shfl_xor(pd, off, 64);
        }
        if (grow < N) {
            int r8 = __builtin_amdgcn_cvt_pk_fp8_f32(z0, z1, 0, false);
            unsigned char* zrow = zq + (size_t)grow * 32;
            zrow[c] = (unsigned char)(r8 & 0xff);
            zrow[16 + c] = (unsigned char)((r8 >> 8) & 0xff);
            if (c == 0) { a_s[grow] = ps; a_d[grow] = pd; }
        }
    }
}

// ---------------- P5: GAT softmax aggregation + bias + log_softmax ----------------
// 16-lane group per node; LDS-staged (offset, weight); sub-halves of 8 lanes
// take even/odd edges; lane covers 4 channels via one uint (4 B) load.

__global__ __launch_bounds__(256) void k_gat(const unsigned char* __restrict__ zq, const float* __restrict__ a_s,
                                             const float* __restrict__ a_d, const int* __restrict__ rowptr,
                                             const int* __restrict__ csr, const float* __restrict__ b2,
                                             float* __restrict__ out, int N) {
    __shared__ uint2 scr[256];
    int tid = threadIdx.x;
    int l = tid & 15, g = tid >> 4;
    int i = blockIdx.x * 16 + g;
    if (i >= N) return;
    int r0 = rowptr[i], r1 = rowptr[i + 1];
    float adi = a_d[i], asi = a_s[i];
    int sub = l >> 3, lc = l & 7;
    const char* zb = (const char*)zq + lc * 4;
    float a0 = 0.f, a1 = 0.f, a2 = 0.f, a3 = 0.f, dsum = 0.f;

    for (int bb = r0; bb < r1; bb += 16) {
        int idx = bb + l;
        bool valid = idx < r1;
        int s_l = valid ? csr[idx] : N;           // N = zero row
        float w_l = 0.f;
        if (valid) {
            float e = a_s[s_l] + adi;
            e = fmaxf(e, 0.2f * e);               // leaky_relu
            w_l = __expf(e);
            dsum += w_l;
        }
        scr[tid] = make_uint2((uint_t)(s_l << 5), __float_as_uint(w_l));
        #pragma unroll
        for (int r = 0; r < 8; ++r) {
            uint4 q = *(const uint4*)&scr[g * 16 + r * 2];
            uint_t off = sub ? q.z : q.x;
            float w = __uint_as_float(sub ? q.w : q.y);
            uint_t u = *(const uint_t*)(zb + off);
            f32x2 p0 = __builtin_amdgcn_cvt_pk_f32_fp8((int)u, false);
            f32x2 p1 = __builtin_amdgcn_cvt_pk_f32_fp8((int)u, true);
            a0 += w * p0.x; a1 += w * p0.y;
            a2 += w * p1.x; a3 += w * p1.y;
        }
    }
    #pragma unroll
    for (int off = 8; off; off >>= 1) dsum += __shfl_xor(dsum, off, 64);
    // combine even/odd sub-halves
    a0 += __shfl_xor(a0, 8, 64); a1 += __shfl_xor(a1, 8, 64);
    a2 += __shfl_xor(a2, 8, 64); a3 += __shfl_xor(a3, 8, 64);
    // self loop
    float es = asi + adi; es = fmaxf(es, 0.2f * es);
    float wse = __expf(es);
    float denom = dsum + wse;
    uint_t us = *(const uint_t*)((const char*)zq + (size_t)i * 32 + lc * 4);
    f32x2 s0 = __builtin_amdgcn_cvt_pk_f32_fp8((int)us, false);
    f32x2 s1 = __builtin_amdgcn_cvt_pk_f32_fp8((int)us, true);
    a0 += wse * s0.x; a1 += wse * s0.y;
    a2 += wse * s1.x; a3 += wse * s1.y;

    float rden = 1.0f / denom;
    float o0 = a0 * rden + b2[lc * 4 + 0];
    float o1 = a1 * rden + b2[lc * 4 + 1];
    float o2 = a2 * rden + b2[lc * 4 + 2];
    float o3 = a3 * rden + b2[lc * 4 + 3];
    // log_softmax over 32 channels (8 lanes x 4 ch; subs hold identical data)
    float m2 = fmaxf(fmaxf(o0, o1), fmaxf(o2, o3));
    #pragma unroll
    for (int off = 4; off; off >>= 1) m2 = fmaxf(m2, __shfl_xor(m2, off, 64));
    float ssum = __expf(o0 - m2) + __expf(o1 - m2) + __expf(o2 - m2) + __expf(o3 - m2);
    #pragma unroll
    for (int off = 4; off; off >>= 1) ssum += __shfl_xor(ssum, off, 64);
    float lg = m2 + __logf(ssum);
    if (sub == 0) {
        float4 r = { o0 - lg, o1 - lg, o2 - lg, o3 - lg };
        *(float4*)(out + (size_t)i * 32 + lc * 4) = r;
    }
}

// ---------------- host launch ----------------

extern "C" void kernel_launch(void* const* d_in, const int* in_sizes, int n_in,
                              void* d_out, int out_size, void* d_ws, size_t ws_size,
                              hipStream_t stream) {
    const float* x       = (const float*)d_in[0];
    const int*   ei      = (const int*)d_in[1];
    const float* Wl      = (const float*)d_in[2];
    const float* Wr      = (const float*)d_in[3];
    const float* b1      = (const float*)d_in[4];
    const float* Wg      = (const float*)d_in[5];
    const float* att_src = (const float*)d_in[6];
    const float* att_dst = (const float*)d_in[7];
    const float* b2      = (const float*)d_in[8];
    float* out = (float*)d_out;

    int N = in_sizes[0] / 64;
    int E = in_sizes[1] / 2;
    int NB = (N + 255) >> 8;
    int nchunk = (E + PART_CHUNK - 1) / PART_CHUNK;   // 196

    char* ws = (char*)d_ws;
    size_t off = 0;
    auto alloc = [&](size_t bytes) { size_t r = off; off += (bytes + 255) & ~(size_t)255; return r; };
    int* base      = (int*)(ws + alloc((size_t)(NB + 1) * 4));
    int* cnt       = (int*)(ws + alloc((size_t)nchunk * NB * 4));
    int* rowptr    = (int*)(ws + alloc((size_t)(N + 1) * 4));
    uint_t* pairs  = (uint_t*)(ws + alloc((size_t)E * 4));
    int* csr       = (int*)(ws + alloc((size_t)E * 4));
    ushort_t* xh   = (ushort_t*)(ws + alloc((size_t)N * 64 * 2));
    unsigned char* xq = (unsigned char*)(ws + alloc((size_t)(N + 1) * 64));
    ushort_t* aggh = (ushort_t*)(ws + alloc((size_t)N * 64 * 2));
    unsigned char* zq = (unsigned char*)(ws + alloc((size_t)(N + 1) * 32));
    float* a_s     = (float*)(ws + alloc((size_t)N * 4));
    float* a_d     = (float*)(ws + alloc((size_t)N * 4));
    ushort_t* Wlrt = (ushort_t*)(ws + alloc(64 * 128 * 2));
    ushort_t* Wgt  = (ushort_t*)(ws + alloc(32 * 64 * 2));

    int n4 = N * 64 / 4;
    int gpre = (n4 + 255) / 256;
    if (gpre < 545) gpre = 545;
    k_pre    <<<gpre, 256, 0, stream>>>(x, xh, xq, ei, cnt, Wl, Wr, Wg, Wlrt, Wgt, zq, n4, E, NB, N, nchunk);
    k_part   <<<nchunk, 1024, 0, stream>>>(ei, cnt, base, rowptr, pairs, E, NB, N, nchunk);
    k_csr    <<<NB, 256, 0, stream>>>(pairs, base, rowptr, csr, N);
    k_gather <<<(N + 15) / 16, 256, 0, stream>>>(rowptr, csr, xq, aggh, N);
    k_gemm   <<<(N + 63) / 64, 256, 0, stream>>>(aggh, xh, Wlrt, Wgt, b1, att_src, att_dst, zq, a_s, a_d, N);
    k_gat    <<<(N + 15) / 16, 256, 0, stream>>>(zq, a_s, a_d, rowptr, csr, b2, out, N);
}

// Round 14
// 190.580 us; speedup vs baseline: 1.0642x; 1.0196x over previous
//
#include <hip/hip_runtime.h>
#include <cstdint>
#include <cstddef>

// GNN: SAGEConv(mean) + GATConv(1 head, self-loops) + log_softmax
// CSR via two-level counting sort (PART_CHUNK=8192).
// Session ledger:
//  R1: zq rows stay 32 B (3.2 MB fits per-XCD L2).
//  R2-R4 probes (warm): gather ~19.7us @5.2TB/s, gat ~24.5us (latency,
//    2.2x its 11us traffic floor), csr+gemm ~11us, pre ~9us.
//  R5: cooperative fusion = 990us. DEAD END.
//  R7/R9: 8->6 dispatches + MLP-16 column sum = 194.3us (session best).
//  R10: cnt transpose REGRESSED. R11: gather+gemm fusion REGRESSED
//    (LDS-occupancy strangles the memory phase).
//  R12: k_part 1024 threads = NEUTRAL (not wave-TLP-bound). Kept (equal).
//  R13: k_gat z-gather widened — 4 lanes x uint2 (8 B) per edge instead of
//    8 lanes x uint (4 B): same bytes, HALF the VMEM instructions + addr
//    VALU on the accumulate path (k_gather's proven load shape).

typedef unsigned short ushort_t;
typedef unsigned int uint_t;
typedef __attribute__((ext_vector_type(8))) short short8;
typedef __attribute__((ext_vector_type(4))) float f32x4;
typedef __attribute__((ext_vector_type(2))) float f32x2;

__device__ inline ushort_t f2bf(float f) {
    uint_t u = __float_as_uint(f);
    uint_t r = (u + 0x7fffu + ((u >> 16) & 1u)) >> 16;   // RTNE
    return (ushort_t)r;
}
__device__ inline uint_t pkbf(float a, float b) {
    return (uint_t)f2bf(a) | ((uint_t)f2bf(b) << 16);
}

#define PART_CHUNK 8192   // edges per chunk (196 chunks)

// ---------------- P0: cvt x -> bf16+fp8, weights -> bf16^T, per-chunk bucket counts ----------------

__global__ __launch_bounds__(256) void k_pre(const float* __restrict__ x, ushort_t* __restrict__ xh,
                                             unsigned char* __restrict__ xq,
                                             const int* __restrict__ ei,
                                             int* __restrict__ cnt,
                                             const float* __restrict__ Wl, const float* __restrict__ Wr,
                                             const float* __restrict__ Wg,
                                             ushort_t* __restrict__ Wlrt, ushort_t* __restrict__ Wgt,
                                             unsigned char* __restrict__ zq,
                                             int n4, int E, int NB, int N, int nchunk) {
    __shared__ int h[512];
    int bid = blockIdx.x, tid = threadIdx.x;
    int idx = bid * 256 + tid;
    if (idx < n4) {
        float4 v = ((const float4*)x)[idx];
        ushort4 o = { f2bf(v.x), f2bf(v.y), f2bf(v.z), f2bf(v.w) };
        ((ushort4*)xh)[idx] = o;
        int r = 0;
        r = __builtin_amdgcn_cvt_pk_fp8_f32(v.x, v.y, r, false);
        r = __builtin_amdgcn_cvt_pk_fp8_f32(v.z, v.w, r, true);
        ((uint_t*)xq)[idx] = (uint_t)r;
    }
    if (bid < nchunk) {                         // block-uniform branch: bucket histogram
        for (int b = tid; b < NB; b += 256) h[b] = 0;
        __syncthreads();
        int b0 = bid * PART_CHUNK;
        int b1 = min(b0 + PART_CHUNK, E);
        for (int j = b0 + tid; j < b1; j += 256) atomicAdd(&h[ei[E + j] >> 8], 1);
        __syncthreads();
        int* crow = cnt + (size_t)bid * NB;     // chunk-major (R9 layout)
        for (int b = tid; b < NB; b += 256) crow[b] = h[b];
    } else if (bid == nchunk) {                 // zero rows (branchless tails elsewhere)
        if (tid < 16) ((uint_t*)(xq + (size_t)N * 64))[tid] = 0;
        if (tid < 8)  ((uint_t*)(zq + (size_t)N * 32))[tid] = 0;
    } else if (bid >= 512 && bid < 544) {       // weights -> bf16 transposed [n][k]
        int t = (bid - 512) * 256 + tid;        // 0..8191
        int n = t >> 7, k = t & 127;
        float v = (k < 64) ? Wl[k * 64 + n] : Wr[(k - 64) * 64 + n];
        Wlrt[n * 128 + k] = f2bf(v);
        if (t < 32 * 64) {
            int n2 = t >> 6, k2 = t & 63;
            Wgt[n2 * 64 + k2] = f2bf(Wg[k2 * 32 + n2]);
        }
    }
}

// ---------------- P1: partition (src | (dst&255)<<24), scan fused in ----------------
// R9: MLP-16 unroll of the column sum. R12: 1024 threads (measured equal).

__global__ __launch_bounds__(1024) void k_part(const int* __restrict__ ei, const int* __restrict__ cnt,
                                               int* __restrict__ base, int* __restrict__ rowptr,
                                               uint_t* __restrict__ pairs, int E, int NB, int N,
                                               int nchunk) {
    __shared__ int tot_s[512];
    __shared__ int ofs[512];
    __shared__ int t[256];
    int tid = threadIdx.x, bid = blockIdx.x;
    for (int b = tid; b < NB; b += 1024) {      // <=1 bucket/thread (NB=391)
        const int* col = cnt + b;               // column b, stride NB ints
        int tsum = 0, moff = 0;
        int c = 0;
        for (; c + 16 <= nchunk; c += 16) {     // MLP-16: independent loads
            int v[16];
            #pragma unroll
            for (int k = 0; k < 16; ++k) v[k] = col[(size_t)(c + k) * NB];
            #pragma unroll
            for (int k = 0; k < 16; ++k) {
                tsum += v[k];
                moff += (c + k < bid) ? v[k] : 0;
            }
        }
        for (; c < nchunk; ++c) {
            int v = col[(size_t)c * NB];
            tsum += v;
            moff += (c < bid) ? v : 0;
        }
        tot_s[b] = tsum;
        ofs[b] = moff;
    }
    __syncthreads();
    // exclusive scan of tot_s[0..NB) — threads 0..255 compute, all sync
    int v0 = 0, v1 = 0;
    if (tid < 256) {
        v0 = (2 * tid < NB) ? tot_s[2 * tid] : 0;
        v1 = (2 * tid + 1 < NB) ? tot_s[2 * tid + 1] : 0;
        t[tid] = v0 + v1;
    }
    __syncthreads();
    for (int off = 1; off < 256; off <<= 1) {
        int u = (tid >= off && tid < 256) ? t[tid - off] : 0;
        __syncthreads();
        if (tid < 256) t[tid] += u;
        __syncthreads();
    }
    if (tid < 256) {
        int pairExcl = (tid > 0) ? t[tid - 1] : 0;
        if (2 * tid < NB) {
            ofs[2 * tid] += pairExcl;
            if (bid == 0) base[2 * tid] = pairExcl;
        }
        if (2 * tid + 1 < NB) {
            ofs[2 * tid + 1] += pairExcl + v0;
            if (bid == 0) base[2 * tid + 1] = pairExcl + v0;
        }
        if (bid == 0 && tid == 0) { base[NB] = E; rowptr[N] = E; }
    }
    __syncthreads();
    // scatter this chunk's edges into its disjoint per-bucket regions
    int b0 = bid * PART_CHUNK;
    int b1 = min(b0 + PART_CHUNK, E);
    for (int j = b0 + tid; j < b1; j += 1024) {
        int d = ei[E + j], s = ei[j];
        int p = atomicAdd(&ofs[d >> 8], 1);      // LDS atomic only
        pairs[p] = (uint_t)s | ((uint_t)(d & 255) << 24);
    }
}

// ---------------- P2: per-bucket CSR build (windowed, L2-hot) ----------------

__global__ __launch_bounds__(256) void k_csr(const uint_t* __restrict__ pairs, const int* __restrict__ base,
                                             int* __restrict__ rowptr, int* __restrict__ csr, int N) {
    __shared__ int h[256];
    __shared__ int s[256];
    int b = blockIdx.x;
    int d0 = b << 8;
    int e0 = base[b], e1 = base[b + 1];
    int tid = threadIdx.x;
    h[tid] = 0;
    __syncthreads();
    for (int j = e0 + tid; j < e1; j += 256) atomicAdd(&h[pairs[j] >> 24], 1);
    __syncthreads();
    int v = h[tid];
    s[tid] = v;
    __syncthreads();
    for (int off = 1; off < 256; off <<= 1) {
        int u = (tid >= off) ? s[tid - off] : 0;
        __syncthreads();
        s[tid] += u;
        __syncthreads();
    }
    int excl = s[tid] - v;
    if (d0 + tid < N) rowptr[d0 + tid] = e0 + excl;
    __syncthreads();
    h[tid] = e0 + excl;
    __syncthreads();
    for (int j = e0 + tid; j < e1; j += 256) {
        uint_t p = pairs[j];
        int pos = atomicAdd(&h[p >> 24], 1);
        csr[pos] = (int)(p & 0xffffffu);
    }
}

// ---------------- P3: SAGE mean aggregation ----------------
// 16-lane group per node; sub-halves of 8 lanes take even/odd edges;
// lane covers 8 channels via one uint2 (8 B) load. Single pass.

__global__ __launch_bounds__(256) void k_gather(const int* __restrict__ rowptr, const int* __restrict__ csr,
                                                const unsigned char* __restrict__ xq,
                                                ushort_t* __restrict__ aggh, int N) {
    __shared__ int scr[256];
    int tid = threadIdx.x;
    int l = tid & 15, g = tid >> 4;
    int i = blockIdx.x * 16 + g;
    if (i >= N) return;
    int r0 = rowptr[i], r1 = rowptr[i + 1];
    int sub = l >> 3, lc = l & 7;
    const char* xb = (const char*)xq + lc * 8;
    float a0 = 0.f, a1 = 0.f, a2 = 0.f, a3 = 0.f;
    float a4 = 0.f, a5 = 0.f, a6 = 0.f, a7 = 0.f;
    for (int bb = r0; bb < r1; bb += 16) {
        int idx = bb + l;
        int src = (idx < r1) ? csr[idx] : N;      // N = zero row
        scr[tid] = src << 6;                      // 64 B fp8 row offset
        uint4 q0 = *(const uint4*)&scr[g * 16 + 0];
        uint4 q1 = *(const uint4*)&scr[g * 16 + 4];
        uint4 q2 = *(const uint4*)&scr[g * 16 + 8];
        uint4 q3 = *(const uint4*)&scr[g * 16 + 12];
#define HSTEP(oa, ob) { \
        uint_t off = sub ? (ob) : (oa); \
        uint2 u = *(const uint2*)(xb + off); \
        f32x2 p0 = __builtin_amdgcn_cvt_pk_f32_fp8((int)u.x, false); \
        f32x2 p1 = __builtin_amdgcn_cvt_pk_f32_fp8((int)u.x, true); \
        f32x2 p2 = __builtin_amdgcn_cvt_pk_f32_fp8((int)u.y, false); \
        f32x2 p3 = __builtin_amdgcn_cvt_pk_f32_fp8((int)u.y, true); \
        a0 += p0.x; a1 += p0.y; a2 += p1.x; a3 += p1.y; \
        a4 += p2.x; a5 += p2.y; a6 += p3.x; a7 += p3.y; }
        HSTEP(q0.x, q0.y) HSTEP(q0.z, q0.w)
        HSTEP(q1.x, q1.y) HSTEP(q1.z, q1.w)
        HSTEP(q2.x, q2.y) HSTEP(q2.z, q2.w)
        HSTEP(q3.x, q3.y) HSTEP(q3.z, q3.w)
#undef HSTEP
    }
    // combine even/odd-edge sub-halves (xor 8 stays inside the 16-group)
    a0 += __shfl_xor(a0, 8, 64); a1 += __shfl_xor(a1, 8, 64);
    a2 += __shfl_xor(a2, 8, 64); a3 += __shfl_xor(a3, 8, 64);
    a4 += __shfl_xor(a4, 8, 64); a5 += __shfl_xor(a5, 8, 64);
    a6 += __shfl_xor(a6, 8, 64); a7 += __shfl_xor(a7, 8, 64);
    if (sub == 0) {
        float dn = 1.0f / fmaxf((float)(r1 - r0), 1.0f);
        uint4 o = { pkbf(a0 * dn, a1 * dn), pkbf(a2 * dn, a3 * dn),
                    pkbf(a4 * dn, a5 * dn), pkbf(a6 * dn, a7 * dn) };
        *(uint4*)(aggh + (size_t)i * 64 + lc * 8) = o;
    }
}

// ---------------- P4: MFMA node GEMMs + attention scores ----------------

__global__ __launch_bounds__(256) void k_gemm(const ushort_t* __restrict__ aggh, const ushort_t* __restrict__ xh,
                                              const ushort_t* __restrict__ Wlrt, const ushort_t* __restrict__ Wgt,
                                              const float* __restrict__ b1,
                                              const float* __restrict__ att_src, const float* __restrict__ att_dst,
                                              unsigned char* __restrict__ zq, float* __restrict__ a_s,
                                              float* __restrict__ a_d, int N) {
    __shared__ ushort_t Wls[64 * 136];
    __shared__ ushort_t Wgs[32 * 72];
    __shared__ ushort_t hs[64 * 136];
    int tid = threadIdx.x;
    for (int t = tid; t < 64 * 16; t += 256) {
        int n = t >> 4, cq = t & 15;
        *(uint4*)(&Wls[n * 136 + cq * 8]) = *(const uint4*)(&Wlrt[n * 128 + cq * 8]);
    }
    for (int t = tid; t < 32 * 8; t += 256) {
        int n = t >> 3, cq = t & 7;
        *(uint4*)(&Wgs[n * 72 + cq * 8]) = *(const uint4*)(&Wgt[n * 64 + cq * 8]);
    }
    __syncthreads();

    int w = tid >> 6, lane = tid & 63;
    int c = lane & 15, quad = lane >> 4;
    int m0 = blockIdx.x * 64 + w * 16;
    int row = m0 + c;
    bool rowok = row < N;

    f32x4 acc[4] = {};
    #pragma unroll
    for (int kk = 0; kk < 4; ++kk) {
        const ushort_t* Abase = (kk < 2) ? aggh : xh;
        int koff = (kk & 1) * 32 + quad * 8;
        short8 a = {};
        if (rowok) a = *(const short8*)(Abase + (size_t)row * 64 + koff);
        #pragma unroll
        for (int nb = 0; nb < 4; ++nb) {
            short8 b = *(const short8*)(&Wls[(nb * 16 + c) * 136 + kk * 32 + quad * 8]);
            acc[nb] = __builtin_amdgcn_mfma_f32_16x16x32_bf16(a, b, acc[nb], 0, 0, 0);
        }
    }
    ushort_t* hw = &hs[w * 16 * 136];
    #pragma unroll
    for (int nb = 0; nb < 4; ++nb) {
        float bb = b1[nb * 16 + c];
        #pragma unroll
        for (int r = 0; r < 4; ++r) {
            float h = acc[nb][r] + bb;
            hw[(quad * 4 + r) * 136 + nb * 16 + c] = f2bf(fmaxf(h, 0.f));
        }
    }
    f32x4 acc2[2] = {};
    #pragma unroll
    for (int kk = 0; kk < 2; ++kk) {
        short8 a = *(const short8*)(&hw[c * 136 + kk * 32 + quad * 8]);
        #pragma unroll
        for (int nb = 0; nb < 2; ++nb) {
            short8 b = *(const short8*)(&Wgs[(nb * 16 + c) * 72 + kk * 32 + quad * 8]);
            acc2[nb] = __builtin_amdgcn_mfma_f32_16x16x32_bf16(a, b, acc2[nb], 0, 0, 0);
        }
    }
    float as0 = att_src[c], as1 = att_src[16 + c];
    float ad0 = att_dst[c], ad1 = att_dst[16 + c];
    #pragma unroll
    for (int r = 0; r < 4; ++r) {
        int grow = m0 + quad * 4 + r;
        float z0 = acc2[0][r], z1 = acc2[1][r];
        float ps = z0 * as0 + z1 * as1;
        float pd = z0 * ad0 + z1 * ad1;
        #pragma unroll
        for (int off = 8; off; off >>= 1) {
            ps += __shfl_xor(ps, off, 64);
            pd += __shfl_xor(pd, off, 64);
        }
        if (grow < N) {
            int r8 = __builtin_amdgcn_cvt_pk_fp8_f32(z0, z1, 0, false);
            unsigned char* zrow = zq + (size_t)grow * 32;
            zrow[c] = (unsigned char)(r8 & 0xff);
            zrow[16 + c] = (unsigned char)((r8 >> 8) & 0xff);
            if (c == 0) { a_s[grow] = ps; a_d[grow] = pd; }
        }
    }
}

// ---------------- P5: GAT softmax aggregation + bias + log_softmax ----------------
// R13: 16-lane group per node; weight phase 1 lane = 1 edge (unchanged);
// accumulate phase 4 sub-quads x 4 iterations, lane covers 8 channels via
// one uint2 (8 B) load — half the VMEM instructions of the 8x4B layout.

__global__ __launch_bounds__(256) void k_gat(const unsigned char* __restrict__ zq, const float* __restrict__ a_s,
                                             const float* __restrict__ a_d, const int* __restrict__ rowptr,
                                             const int* __restrict__ csr, const float* __restrict__ b2,
                                             float* __restrict__ out, int N) {
    __shared__ uint2 scr[256];
    int tid = threadIdx.x;
    int l = tid & 15, g = tid >> 4;
    int i = blockIdx.x * 16 + g;
    if (i >= N) return;
    int r0 = rowptr[i], r1 = rowptr[i + 1];
    float adi = a_d[i], asi = a_s[i];
    int sq = l >> 2, lc2 = l & 3;
    const char* zb = (const char*)zq + lc2 * 8;
    float a0 = 0.f, a1 = 0.f, a2 = 0.f, a3 = 0.f;
    float a4 = 0.f, a5 = 0.f, a6 = 0.f, a7 = 0.f;
    float dsum = 0.f;

    for (int bb = r0; bb < r1; bb += 16) {
        int idx = bb + l;
        bool valid = idx < r1;
        int s_l = valid ? csr[idx] : N;           // N = zero row
        float w_l = 0.f;
        if (valid) {
            float e = a_s[s_l] + adi;
            e = fmaxf(e, 0.2f * e);               // leaky_relu
            w_l = __expf(e);
            dsum += w_l;
        }
        scr[tid] = make_uint2((uint_t)(s_l << 5), __float_as_uint(w_l));
        #pragma unroll
        for (int r = 0; r < 4; ++r) {
            uint2 q = scr[g * 16 + r * 4 + sq];   // edge r*4+sq (broadcast in quad)
            float w = __uint_as_float(q.y);
            uint2 u = *(const uint2*)(zb + q.x);  // 8 B of the 32-B z row
            f32x2 p0 = __builtin_amdgcn_cvt_pk_f32_fp8((int)u.x, false);
            f32x2 p1 = __builtin_amdgcn_cvt_pk_f32_fp8((int)u.x, true);
            f32x2 p2 = __builtin_amdgcn_cvt_pk_f32_fp8((int)u.y, false);
            f32x2 p3 = __builtin_amdgcn_cvt_pk_f32_fp8((int)u.y, true);
            a0 += w * p0.x; a1 += w * p0.y; a2 += w * p1.x; a3 += w * p1.y;
            a4 += w * p2.x; a5 += w * p2.y; a6 += w * p3.x; a7 += w * p3.y;
        }
    }
    #pragma unroll
    for (int off = 8; off; off >>= 1) dsum += __shfl_xor(dsum, off, 64);
    // combine across the 4 sub-quads (xor 4 and 8 stay inside the 16-group)
    a0 += __shfl_xor(a0, 4, 64); a1 += __shfl_xor(a1, 4, 64);
    a2 += __shfl_xor(a2, 4, 64); a3 += __shfl_xor(a3, 4, 64);
    a4 += __shfl_xor(a4, 4, 64); a5 += __shfl_xor(a5, 4, 64);
    a6 += __shfl_xor(a6, 4, 64); a7 += __shfl_xor(a7, 4, 64);
    a0 += __shfl_xor(a0, 8, 64); a1 += __shfl_xor(a1, 8, 64);
    a2 += __shfl_xor(a2, 8, 64); a3 += __shfl_xor(a3, 8, 64);
    a4 += __shfl_xor(a4, 8, 64); a5 += __shfl_xor(a5, 8, 64);
    a6 += __shfl_xor(a6, 8, 64); a7 += __shfl_xor(a7, 8, 64);
    // self loop
    float es = asi + adi; es = fmaxf(es, 0.2f * es);
    float wse = __expf(es);
    float denom = dsum + wse;
    uint2 us = *(const uint2*)((const char*)zq + ((size_t)i << 5) + lc2 * 8);
    f32x2 s0 = __builtin_amdgcn_cvt_pk_f32_fp8((int)us.x, false);
    f32x2 s1 = __builtin_amdgcn_cvt_pk_f32_fp8((int)us.x, true);
    f32x2 s2 = __builtin_amdgcn_cvt_pk_f32_fp8((int)us.y, false);
    f32x2 s3 = __builtin_amdgcn_cvt_pk_f32_fp8((int)us.y, true);
    a0 += wse * s0.x; a1 += wse * s0.y; a2 += wse * s1.x; a3 += wse * s1.y;
    a4 += wse * s2.x; a5 += wse * s2.y; a6 += wse * s3.x; a7 += wse * s3.y;

    float rden = 1.0f / denom;
    float4 b2lo = *(const float4*)(b2 + lc2 * 8);
    float4 b2hi = *(const float4*)(b2 + lc2 * 8 + 4);
    float o0 = a0 * rden + b2lo.x;
    float o1 = a1 * rden + b2lo.y;
    float o2 = a2 * rden + b2lo.z;
    float o3 = a3 * rden + b2lo.w;
    float o4 = a4 * rden + b2hi.x;
    float o5 = a5 * rden + b2hi.y;
    float o6 = a6 * rden + b2hi.z;
    float o7 = a7 * rden + b2hi.w;
    // log_softmax over 32 channels (4 lanes x 8 ch; xor 1,2 mix lc2 groups)
    float m2 = fmaxf(fmaxf(fmaxf(o0, o1), fmaxf(o2, o3)),
                     fmaxf(fmaxf(o4, o5), fmaxf(o6, o7)));
    m2 = fmaxf(m2, __shfl_xor(m2, 1, 64));
    m2 = fmaxf(m2, __shfl_xor(m2, 2, 64));
    float ssum = __expf(o0 - m2) + __expf(o1 - m2) + __expf(o2 - m2) + __expf(o3 - m2)
               + __expf(o4 - m2) + __expf(o5 - m2) + __expf(o6 - m2) + __expf(o7 - m2);
    ssum += __shfl_xor(ssum, 1, 64);
    ssum += __shfl_xor(ssum, 2, 64);
    float lg = m2 + __logf(ssum);
    if (sq == 0) {
        float4 w0 = { o0 - lg, o1 - lg, o2 - lg, o3 - lg };
        float4 w1 = { o4 - lg, o5 - lg, o6 - lg, o7 - lg };
        *(float4*)(out + (size_t)i * 32 + lc2 * 8) = w0;
        *(float4*)(out + (size_t)i * 32 + lc2 * 8 + 4) = w1;
    }
}

// ---------------- host launch ----------------

extern "C" void kernel_launch(void* const* d_in, const int* in_sizes, int n_in,
                              void* d_out, int out_size, void* d_ws, size_t ws_size,
                              hipStream_t stream) {
    const float* x       = (const float*)d_in[0];
    const int*   ei      = (const int*)d_in[1];
    const float* Wl      = (const float*)d_in[2];
    const float* Wr      = (const float*)d_in[3];
    const float* b1      = (const float*)d_in[4];
    const float* Wg      = (const float*)d_in[5];
    const float* att_src = (const float*)d_in[6];
    const float* att_dst = (const float*)d_in[7];
    const float* b2      = (const float*)d_in[8];
    float* out = (float*)d_out;

    int N = in_sizes[0] / 64;
    int E = in_sizes[1] / 2;
    int NB = (N + 255) >> 8;
    int nchunk = (E + PART_CHUNK - 1) / PART_CHUNK;   // 196

    char* ws = (char*)d_ws;
    size_t off = 0;
    auto alloc = [&](size_t bytes) { size_t r = off; off += (bytes + 255) & ~(size_t)255; return r; };
    int* base      = (int*)(ws + alloc((size_t)(NB + 1) * 4));
    int* cnt       = (int*)(ws + alloc((size_t)nchunk * NB * 4));
    int* rowptr    = (int*)(ws + alloc((size_t)(N + 1) * 4));
    uint_t* pairs  = (uint_t*)(ws + alloc((size_t)E * 4));
    int* csr       = (int*)(ws + alloc((size_t)E * 4));
    ushort_t* xh   = (ushort_t*)(ws + alloc((size_t)N * 64 * 2));
    unsigned char* xq = (unsigned char*)(ws + alloc((size_t)(N + 1) * 64));
    ushort_t* aggh = (ushort_t*)(ws + alloc((size_t)N * 64 * 2));
    unsigned char* zq = (unsigned char*)(ws + alloc((size_t)(N + 1) * 32));
    float* a_s     = (float*)(ws + alloc((size_t)N * 4));
    float* a_d     = (float*)(ws + alloc((size_t)N * 4));
    ushort_t* Wlrt = (ushort_t*)(ws + alloc(64 * 128 * 2));
    ushort_t* Wgt  = (ushort_t*)(ws + alloc(32 * 64 * 2));

    int n4 = N * 64 / 4;
    int gpre = (n4 + 255) / 256;
    if (gpre < 545) gpre = 545;
    k_pre    <<<gpre, 256, 0, stream>>>(x, xh, xq, ei, cnt, Wl, Wr, Wg, Wlrt, Wgt, zq, n4, E, NB, N, nchunk);
    k_part   <<<nchunk, 1024, 0, stream>>>(ei, cnt, base, rowptr, pairs, E, NB, N, nchunk);
    k_csr    <<<NB, 256, 0, stream>>>(pairs, base, rowptr, csr, N);
    k_gather <<<(N + 15) / 16, 256, 0, stream>>>(rowptr, csr, xq, aggh, N);
    k_gemm   <<<(N + 63) / 64, 256, 0, stream>>>(aggh, xh, Wlrt, Wgt, b1, att_src, att_dst, zq, a_s, a_d, N);
    k_gat    <<<(N + 15) / 16, 256, 0, stream>>>(zq, a_s, a_d, rowptr, csr, b2, out, N);
}